// Round 9
// baseline (228.596 us; speedup 1.0000x reference)
//
#include <hip/hip_runtime.h>
#include <hip/hip_bf16.h>

#define SEQ 4096
#define HID 768
#define NHEAD 12
#define HDIM 64
#define KVB 64
#define NT (SEQ / KVB)   // 64
#define PBK 64
#define PNT (HID / PBK)  // 12

typedef __attribute__((ext_vector_type(8))) short bf16x8;
typedef __attribute__((ext_vector_type(4))) float f32x4;
typedef __attribute__((ext_vector_type(4))) short s16x4;

static __device__ __forceinline__ short f2bf(float f) {
    unsigned u = __builtin_bit_cast(unsigned, f);
    unsigned r = (u + 0x7fffu + ((u >> 16) & 1u)) >> 16;
    return (short)r;
}
static __device__ __forceinline__ unsigned cvtpk(float lo, float hi) {
    unsigned r;
    asm("v_cvt_pk_bf16_f32 %0, %1, %2" : "=v"(r) : "v"(lo), "v"(hi));
    return r;
}
static __device__ __forceinline__ float max3f(float a, float b, float c) {
    float r;
    asm("v_max3_f32 %0, %1, %2, %3" : "=v"(r) : "v"(a), "v"(b), "v"(c));
    return r;
}
static __device__ __forceinline__ void glds16(const void* g, void* l) {
    __builtin_amdgcn_global_load_lds(
        (const __attribute__((address_space(1))) unsigned*)g,
        (__attribute__((address_space(3))) unsigned*)l, 16, 0, 0);
}

// ---------------------------------------------------------------------------
// fp32 -> bf16 casts + mask*log2e prep
// ---------------------------------------------------------------------------
__global__ __launch_bounds__(256) void cast_bf16_kernel(
    const float* __restrict__ src, short* __restrict__ dst)
{
    const size_t i = (size_t)blockIdx.x * 256 + threadIdx.x;
    const float4* s = reinterpret_cast<const float4*>(src) + i * 2;
    const float4 a = s[0], b = s[1];
    bf16x8 o;
    o[0] = f2bf(a.x); o[1] = f2bf(a.y); o[2] = f2bf(a.z); o[3] = f2bf(a.w);
    o[4] = f2bf(b.x); o[5] = f2bf(b.y); o[6] = f2bf(b.z); o[7] = f2bf(b.w);
    reinterpret_cast<bf16x8*>(dst)[i] = o;
}

__global__ __launch_bounds__(256) void cast_w_kernel(
    const float* __restrict__ Wq, const float* __restrict__ Wk,
    const float* __restrict__ Wv, short* __restrict__ dst)
{
    const int z = blockIdx.y;
    const float* src = (z == 0) ? Wq : ((z == 1) ? Wk : Wv);
    const size_t i = (size_t)blockIdx.x * 256 + threadIdx.x;
    const float4* s = reinterpret_cast<const float4*>(src) + i * 2;
    const float4 a = s[0], b = s[1];
    bf16x8 o;
    o[0] = f2bf(a.x); o[1] = f2bf(a.y); o[2] = f2bf(a.z); o[3] = f2bf(a.w);
    o[4] = f2bf(b.x); o[5] = f2bf(b.y); o[6] = f2bf(b.z); o[7] = f2bf(b.w);
    reinterpret_cast<bf16x8*>(dst + (size_t)z * HID * HID)[i] = o;
}

__global__ __launch_bounds__(256) void maskml_kernel(
    const float* __restrict__ m, float* __restrict__ o)
{
    const float ML = 1.44269504088896340736f;
    const int i = blockIdx.x * 256 + threadIdx.x;   // 1024 threads, float4 each
    float4 v = reinterpret_cast<const float4*>(m)[i];
    v.x *= ML; v.y *= ML; v.z *= ML; v.w *= ML;
    reinterpret_cast<float4*>(o)[i] = v;
}

// ---------------------------------------------------------------------------
// QKV projection, LDS-staged. Tile 128x128, BK=64, dbuf 64KB.
// Q output pre-scaled by 0.125*log2e (folds the softmax scale).
// ---------------------------------------------------------------------------
__global__ __launch_bounds__(256) void qkv_proj_kernel(
    const short* __restrict__ hsb, const short* __restrict__ Wb,
    const float* __restrict__ bq, const float* __restrict__ bk,
    const float* __restrict__ bv,
    short* __restrict__ Qb, short* __restrict__ Kb, short* __restrict__ Vt)
{
    __shared__ __align__(16) char lds[65536];
    const int z = blockIdx.z;
    const float* bias = (z == 0) ? bq : ((z == 1) ? bk : bv);

    const int lane = threadIdx.x & 63;
    const int w    = threadIdx.x >> 6;
    const int lr = lane & 15, hi = lane >> 4;
    const int wi = w >> 1, wj = w & 1;

    const short* Ag; const short* Bg; int ar0, br0;
    if (z < 2) { Ag = Wb + (size_t)z * HID * HID; ar0 = blockIdx.x * 128;
                 Bg = hsb;                        br0 = blockIdx.y * 128; }
    else       { Ag = hsb;                        ar0 = blockIdx.y * 128;
                 Bg = Wb + (size_t)2 * HID * HID; br0 = blockIdx.x * 128; }

    const int rsub = lane >> 3;
    const int c16  = (lane & 7) ^ rsub;

    auto stage = [&](int t, int buf) {
        const int k0 = t * PBK;
#pragma unroll
        for (int c = 0; c < 4; ++c) {
            const int ch = w * 4 + c;
            const int row = ch * 8 + rsub;
            glds16(Ag + (size_t)(ar0 + row) * HID + k0 + c16 * 8,
                   lds + buf * 16384 + ch * 1024);
            glds16(Bg + (size_t)(br0 + row) * HID + k0 + c16 * 8,
                   lds + 32768 + buf * 16384 + ch * 1024);
        }
    };

    stage(0, 0);
    f32x4 acc[4][4] = {};

    for (int t = 0; t < PNT; ++t) {
        asm volatile("s_waitcnt vmcnt(0)" ::: "memory");
        __builtin_amdgcn_s_barrier();
        __builtin_amdgcn_sched_barrier(0);
        if (t + 1 < PNT) stage(t + 1, (t + 1) & 1);
        const char* LA = lds + (t & 1) * 16384;
        const char* LB = lds + 32768 + (t & 1) * 16384;
#pragma unroll
        for (int ks = 0; ks < 2; ++ks) {
            bf16x8 af[4], bf_[4];
#pragma unroll
            for (int i = 0; i < 4; ++i) {
                const int rowA = wi * 64 + i * 16 + lr;
                af[i] = *reinterpret_cast<const bf16x8*>(
                    LA + rowA * 128 + (((ks * 4 + hi) ^ (rowA & 7)) << 4));
                const int rowB = wj * 64 + i * 16 + lr;
                bf_[i] = *reinterpret_cast<const bf16x8*>(
                    LB + rowB * 128 + (((ks * 4 + hi) ^ (rowB & 7)) << 4));
            }
            __builtin_amdgcn_s_setprio(1);
#pragma unroll
            for (int ia = 0; ia < 4; ++ia)
#pragma unroll
                for (int ib = 0; ib < 4; ++ib)
                    acc[ia][ib] = __builtin_amdgcn_mfma_f32_16x16x32_bf16(
                        af[ia], bf_[ib], acc[ia][ib], 0, 0, 0);
            __builtin_amdgcn_s_setprio(0);
        }
    }

    const float SCQ = 0.125f * 1.44269504088896340736f;
    if (z < 2) {
        short* outp = (z == 0) ? Qb : Kb;
        const float sc = (z == 0) ? SCQ : 1.0f;
#pragma unroll
        for (int ia = 0; ia < 4; ++ia) {
            const int nb = ar0 + wi * 64 + ia * 16 + hi * 4;
            const float4 b4 = *reinterpret_cast<const float4*>(bias + nb);
#pragma unroll
            for (int ib = 0; ib < 4; ++ib) {
                const int m = br0 + wj * 64 + ib * 16 + lr;
                s16x4 v;
                v[0] = f2bf((acc[ia][ib][0] + b4.x) * sc);
                v[1] = f2bf((acc[ia][ib][1] + b4.y) * sc);
                v[2] = f2bf((acc[ia][ib][2] + b4.z) * sc);
                v[3] = f2bf((acc[ia][ib][3] + b4.w) * sc);
                *reinterpret_cast<s16x4*>(outp + (size_t)m * HID + nb) = v;
            }
        }
    } else {
#pragma unroll
        for (int ib = 0; ib < 4; ++ib) {
            const int n = br0 + wj * 64 + ib * 16 + lr;
            const float bb = bias[n];
#pragma unroll
            for (int ia = 0; ia < 4; ++ia) {
                const int mb = ar0 + wi * 64 + ia * 16 + hi * 4;
                s16x4 v;
                v[0] = f2bf(acc[ia][ib][0] + bb);
                v[1] = f2bf(acc[ia][ib][1] + bb);
                v[2] = f2bf(acc[ia][ib][2] + bb);
                v[3] = f2bf(acc[ia][ib][3] + bb);
                *reinterpret_cast<s16x4*>(Vt + (size_t)n * SEQ + mb) = v;
            }
        }
    }
}

// ---------------------------------------------------------------------------
// Flash attention, ALL-REGISTER K/V path (no LDS staging, no main-loop
// barriers). 64q blocks, 4 waves = (qh 2) x (kh 2), each wave 32q x 32k.
// Per tile each wave loads its 4 K-frags + 4 V-frags + 2 mask C-inits
// straight into registers (L1/L2-resident; twin qh-wave hits L1).
// Depth-1 software pipeline: issue t+1's 10 loads, compute t -> compiler
// emits counted vmcnt. Per-lane deferred-max softmax; zero-shuffle P.
// LDS 18KB used only for the final kh-merge (one barrier per kernel).
// ---------------------------------------------------------------------------
__global__ __launch_bounds__(256, 3) void attn_kernel(
    const short* __restrict__ Qb, const short* __restrict__ Kb,
    const short* __restrict__ Vt, const float* __restrict__ maskml,
    float* __restrict__ out)
{
    __shared__ __align__(16) char lds[18432];
    const int tid  = threadIdx.x;
    const int lane = tid & 63;
    const int w    = tid >> 6;
    const int lr = lane & 15, hi = lane >> 4;
    const int qh = w >> 1, kh = w & 1;       // wave = (q-half, key-half)
    const int h  = blockIdx.y;
    const int q0 = blockIdx.x * 64 + qh * 32;

    // ---- per-lane load offsets (elements)
    const int kbase = ((lr >> 2) * 8) + (lr & 3) + kh * 32;  // key-permutation
    const int oK0 = kbase * HID + h * HDIM + hi * 8;
    const int oK1 = oK0 + 32;
    const int oK2 = (kbase + 4) * HID + h * HDIM + hi * 8;
    const int oK3 = oK2 + 32;
    int oV[4];
#pragma unroll
    for (int dg = 0; dg < 4; ++dg)
        oV[dg] = (h * HDIM + dg * 16 + lr) * SEQ + kh * 32 + hi * 8;
    const int oM = kh * 32 + hi * 8;

    struct KV {
        bf16x8 k00, k01, k10, k11;
        bf16x8 v0, v1, v2, v3;
        f32x4 ci0, ci1;
    };
    auto loadKV = [&](int t) {
        KV f;
        const short* k = Kb + (size_t)t * KVB * HID;
        f.k00 = *reinterpret_cast<const bf16x8*>(k + oK0);
        f.k01 = *reinterpret_cast<const bf16x8*>(k + oK1);
        f.k10 = *reinterpret_cast<const bf16x8*>(k + oK2);
        f.k11 = *reinterpret_cast<const bf16x8*>(k + oK3);
        const short* v = Vt + t * KVB;
        f.v0 = *reinterpret_cast<const bf16x8*>(v + oV[0]);
        f.v1 = *reinterpret_cast<const bf16x8*>(v + oV[1]);
        f.v2 = *reinterpret_cast<const bf16x8*>(v + oV[2]);
        f.v3 = *reinterpret_cast<const bf16x8*>(v + oV[3]);
        const float* m = maskml + t * KVB;
        f.ci0 = *reinterpret_cast<const f32x4*>(m + oM);
        f.ci1 = *reinterpret_cast<const f32x4*>(m + oM + 4);
        return f;
    };

    // ---- Q fragments (pre-scaled by 0.125*log2e at projection)
    const short* qp = Qb + (size_t)(q0 + lr) * HID + h * HDIM + hi * 8;
    const bf16x8 qf0 = *reinterpret_cast<const bf16x8*>(qp);
    const bf16x8 qf1 = *reinterpret_cast<const bf16x8*>(qp + 32);
    const bf16x8 qg0 = *reinterpret_cast<const bf16x8*>(qp + 16 * HID);
    const bf16x8 qg1 = *reinterpret_cast<const bf16x8*>(qp + 16 * HID + 32);

    f32x4 acc[4][2] = {};                     // [dg][qg]
    float m_r[2] = {-INFINITY, -INFINITY};
    float ls[2]  = {0.f, 0.f};

    KV cur = loadKV(0);

    for (int t = 0; t < NT; ++t) {
        // issue next tile's loads (branchless wrap at the tail)
        KV nxt = loadKV((t + 1) & (NT - 1));

        // ---- QK^T (key-permuted), C-init = mask*log2e
        f32x4 z[2][2];   // [kg][qg]
        z[0][0] = cur.ci0; z[0][1] = cur.ci0;
        z[1][0] = cur.ci1; z[1][1] = cur.ci1;
        __builtin_amdgcn_s_setprio(1);
        z[0][0] = __builtin_amdgcn_mfma_f32_16x16x32_bf16(cur.k00, qf0, z[0][0], 0, 0, 0);
        z[0][0] = __builtin_amdgcn_mfma_f32_16x16x32_bf16(cur.k01, qf1, z[0][0], 0, 0, 0);
        z[0][1] = __builtin_amdgcn_mfma_f32_16x16x32_bf16(cur.k00, qg0, z[0][1], 0, 0, 0);
        z[0][1] = __builtin_amdgcn_mfma_f32_16x16x32_bf16(cur.k01, qg1, z[0][1], 0, 0, 0);
        z[1][0] = __builtin_amdgcn_mfma_f32_16x16x32_bf16(cur.k10, qf0, z[1][0], 0, 0, 0);
        z[1][0] = __builtin_amdgcn_mfma_f32_16x16x32_bf16(cur.k11, qf1, z[1][0], 0, 0, 0);
        z[1][1] = __builtin_amdgcn_mfma_f32_16x16x32_bf16(cur.k10, qg0, z[1][1], 0, 0, 0);
        z[1][1] = __builtin_amdgcn_mfma_f32_16x16x32_bf16(cur.k11, qg1, z[1][1], 0, 0, 0);
        __builtin_amdgcn_s_setprio(0);

        // ---- e = exp2(z - m), per-lane (no cross-lane ops in common path)
        float e_[2][2][4];
#pragma unroll
        for (int kg = 0; kg < 2; ++kg)
#pragma unroll
            for (int qg = 0; qg < 2; ++qg)
#pragma unroll
                for (int r = 0; r < 4; ++r)
                    e_[kg][qg][r] = exp2f(z[kg][qg][r] - m_r[qg]);

        // ---- per-lane violation check: any e > 2^8?
        const float pa = max3f(e_[0][0][0], e_[0][0][1], e_[0][0][2]);
        const float pb = max3f(e_[0][0][3], e_[0][1][0], e_[0][1][1]);
        const float pc = max3f(e_[0][1][2], e_[0][1][3], e_[1][0][0]);
        const float pd = max3f(e_[1][0][1], e_[1][0][2], e_[1][0][3]);
        const float pe = max3f(e_[1][1][0], e_[1][1][1], e_[1][1][2]);
        const float pmax = max3f(fmaxf(pa, pb), fmaxf(pc, pd),
                                 fmaxf(pe, e_[1][1][3]));
        if (__ballot(pmax > 256.f)) {
            // rare recovery: full cross-lane max, rescale, recompute e
#pragma unroll
            for (int qg = 0; qg < 2; ++qg) {
                float t_ = fmaxf(
                    max3f(z[0][qg][0], z[0][qg][1], z[0][qg][2]),
                    max3f(fmaxf(z[0][qg][3], z[1][qg][0]),
                          fmaxf(z[1][qg][1], z[1][qg][2]), z[1][qg][3]));
                t_ = fmaxf(t_, __shfl_xor(t_, 16));
                t_ = fmaxf(t_, __shfl_xor(t_, 32));
                const float newm = fmaxf(m_r[qg], t_);
                const float sc = exp2f(fmaxf(m_r[qg] - newm, -128.f));
                ls[qg] *= sc;
#pragma unroll
                for (int dg = 0; dg < 4; ++dg) acc[dg][qg] *= sc;
                m_r[qg] = newm;
#pragma unroll
                for (int kg = 0; kg < 2; ++kg)
#pragma unroll
                    for (int r = 0; r < 4; ++r)
                        e_[kg][qg][r] = exp2f(z[kg][qg][r] - newm);
            }
        }

        // ---- accumulate l, pack P (zero-shuffle)
        union { unsigned u[4]; bf16x8 v; } P[2];
#pragma unroll
        for (int qg = 0; qg < 2; ++qg) {
            ls[qg] += ((e_[0][qg][0] + e_[0][qg][1]) + (e_[0][qg][2] + e_[0][qg][3]))
                    + ((e_[1][qg][0] + e_[1][qg][1]) + (e_[1][qg][2] + e_[1][qg][3]));
            P[qg].u[0] = cvtpk(e_[0][qg][0], e_[0][qg][1]);
            P[qg].u[1] = cvtpk(e_[0][qg][2], e_[0][qg][3]);
            P[qg].u[2] = cvtpk(e_[1][qg][0], e_[1][qg][1]);
            P[qg].u[3] = cvtpk(e_[1][qg][2], e_[1][qg][3]);
        }

        // ---- PV: O[d][q] += V[d][k]·P[k][q] over this wave's 32 keys
        __builtin_amdgcn_s_setprio(1);
        acc[0][0] = __builtin_amdgcn_mfma_f32_16x16x32_bf16(cur.v0, P[0].v, acc[0][0], 0, 0, 0);
        acc[0][1] = __builtin_amdgcn_mfma_f32_16x16x32_bf16(cur.v0, P[1].v, acc[0][1], 0, 0, 0);
        acc[1][0] = __builtin_amdgcn_mfma_f32_16x16x32_bf16(cur.v1, P[0].v, acc[1][0], 0, 0, 0);
        acc[1][1] = __builtin_amdgcn_mfma_f32_16x16x32_bf16(cur.v1, P[1].v, acc[1][1], 0, 0, 0);
        acc[2][0] = __builtin_amdgcn_mfma_f32_16x16x32_bf16(cur.v2, P[0].v, acc[2][0], 0, 0, 0);
        acc[2][1] = __builtin_amdgcn_mfma_f32_16x16x32_bf16(cur.v2, P[1].v, acc[2][1], 0, 0, 0);
        acc[3][0] = __builtin_amdgcn_mfma_f32_16x16x32_bf16(cur.v3, P[0].v, acc[3][0], 0, 0, 0);
        acc[3][1] = __builtin_amdgcn_mfma_f32_16x16x32_bf16(cur.v3, P[1].v, acc[3][1], 0, 0, 0);
        __builtin_amdgcn_s_setprio(0);

        cur = nxt;
    }

    // ---- reduce l across hi-groups (per qg)
#pragma unroll
    for (int qg = 0; qg < 2; ++qg) {
        float t_ = ls[qg];
        t_ += __shfl_xor(t_, 16);
        t_ += __shfl_xor(t_, 32);
        ls[qg] = t_;
    }

    // ---- flash-merge the two key-halves through LDS
    float* mg  = (float*)lds;                 // [qh][dg*2+qg][lane] f32x4 = 16KB
    float* mlb = (float*)(lds + 16384);       // [qh][qg][lane][2] = 2KB
    if (kh == 1) {
#pragma unroll
        for (int qg = 0; qg < 2; ++qg) {
            float2 v0; v0.x = m_r[qg]; v0.y = ls[qg];
            *reinterpret_cast<float2*>(mlb + (((qh * 2 + qg) * 64 + lane) * 2)) = v0;
        }
#pragma unroll
        for (int dg = 0; dg < 4; ++dg)
#pragma unroll
            for (int qg = 0; qg < 2; ++qg)
                *reinterpret_cast<f32x4*>(
                    mg + ((qh * 8 + dg * 2 + qg) * 64 + lane) * 4) = acc[dg][qg];
    }
    __syncthreads();
    if (kh == 0) {
        float sc0[2], sc1[2], rl[2];
#pragma unroll
        for (int qg = 0; qg < 2; ++qg) {
            const float2 v = *reinterpret_cast<const float2*>(
                mlb + (((qh * 2 + qg) * 64 + lane) * 2));
            const float mm = fmaxf(m_r[qg], v.x);
            sc0[qg] = exp2f(fmaxf(m_r[qg] - mm, -128.f));
            sc1[qg] = exp2f(fmaxf(v.x - mm, -128.f));
            rl[qg] = 1.0f / (ls[qg] * sc0[qg] + v.y * sc1[qg]);
        }
#pragma unroll
        for (int dg = 0; dg < 4; ++dg) {
#pragma unroll
            for (int qg = 0; qg < 2; ++qg) {
                const f32x4 o1 = *reinterpret_cast<const f32x4*>(
                    mg + ((qh * 8 + dg * 2 + qg) * 64 + lane) * 4);
                const f32x4 of = (acc[dg][qg] * sc0[qg] + o1 * sc1[qg]) * rl[qg];
                float* op = out + (size_t)(q0 + qg * 16 + lr) * HID
                          + h * HDIM + dg * 16 + hi * 4;
                *reinterpret_cast<f32x4*>(op) = of;
            }
        }
    }
}

// ---------------------------------------------------------------------------
extern "C" void kernel_launch(void* const* d_in, const int* in_sizes, int n_in,
                              void* d_out, int out_size, void* d_ws, size_t ws_size,
                              hipStream_t stream) {
    const float* hs   = (const float*)d_in[0];
    const float* mask = (const float*)d_in[1];
    const float* Wq   = (const float*)d_in[2];
    const float* bq   = (const float*)d_in[3];
    const float* Wk   = (const float*)d_in[4];
    const float* bk   = (const float*)d_in[5];
    const float* Wv   = (const float*)d_in[6];
    const float* bv   = (const float*)d_in[7];

    short* Qb = (short*)d_ws;                       // bf16 [SEQ][HID], pre-scaled
    short* Kb = Qb + (size_t)SEQ * HID;             // bf16 [SEQ][HID]
    short* Vt = Kb + (size_t)SEQ * HID;             // bf16 [HID][SEQ]
    float* maskML = (float*)(Vt + (size_t)HID * SEQ);  // f32 [SEQ]
    float* out = (float*)d_out;

    // bf16 scratch carved from d_out (attn overwrites it at the very end)
    short* hsb = (short*)d_out;
    short* Wb  = hsb + (size_t)SEQ * HID;

    cast_bf16_kernel<<<dim3(SEQ * HID / 2048), 256, 0, stream>>>(hs, hsb);
    cast_w_kernel<<<dim3(HID * HID / 2048, 3), 256, 0, stream>>>(Wq, Wk, Wv, Wb);
    maskml_kernel<<<dim3(SEQ / 1024), 256, 0, stream>>>(mask, maskML);

    qkv_proj_kernel<<<dim3(HID / 128, SEQ / 128, 3), 256, 0, stream>>>(
        hsb, Wb, bq, bk, bv, Qb, Kb, Vt);

    attn_kernel<<<dim3(SEQ / KVB, NHEAD), 256, 0, stream>>>(Qb, Kb, Vt, maskML, out);
}

// Round 10
// 139.272 us; speedup vs baseline: 1.6414x; 1.6414x over previous
//
#include <hip/hip_runtime.h>
#include <hip/hip_bf16.h>

#define SEQ 4096
#define HID 768
#define NHEAD 12
#define HDIM 64
#define KVB 64
#define NT (SEQ / KVB)   // 64
#define PBK 64
#define PNT (HID / PBK)  // 12

typedef __attribute__((ext_vector_type(8))) short bf16x8;
typedef __attribute__((ext_vector_type(4))) float f32x4;
typedef __attribute__((ext_vector_type(4))) short s16x4;

static __device__ __forceinline__ short f2bf(float f) {
    unsigned u = __builtin_bit_cast(unsigned, f);
    unsigned r = (u + 0x7fffu + ((u >> 16) & 1u)) >> 16;
    return (short)r;
}
static __device__ __forceinline__ unsigned cvtpk(float lo, float hi) {
    unsigned r;
    asm("v_cvt_pk_bf16_f32 %0, %1, %2" : "=v"(r) : "v"(lo), "v"(hi));
    return r;
}
static __device__ __forceinline__ float max3f(float a, float b, float c) {
    float r;
    asm("v_max3_f32 %0, %1, %2, %3" : "=v"(r) : "v"(a), "v"(b), "v"(c));
    return r;
}
static __device__ __forceinline__ void glds16(const void* g, void* l) {
    __builtin_amdgcn_global_load_lds(
        (const __attribute__((address_space(1))) unsigned*)g,
        (__attribute__((address_space(3))) unsigned*)l, 16, 0, 0);
}

// ---------------------------------------------------------------------------
// fp32 -> bf16 casts + mask*log2e prep
// ---------------------------------------------------------------------------
__global__ __launch_bounds__(256) void cast_bf16_kernel(
    const float* __restrict__ src, short* __restrict__ dst)
{
    const size_t i = (size_t)blockIdx.x * 256 + threadIdx.x;
    const float4* s = reinterpret_cast<const float4*>(src) + i * 2;
    const float4 a = s[0], b = s[1];
    bf16x8 o;
    o[0] = f2bf(a.x); o[1] = f2bf(a.y); o[2] = f2bf(a.z); o[3] = f2bf(a.w);
    o[4] = f2bf(b.x); o[5] = f2bf(b.y); o[6] = f2bf(b.z); o[7] = f2bf(b.w);
    reinterpret_cast<bf16x8*>(dst)[i] = o;
}

__global__ __launch_bounds__(256) void cast_w_kernel(
    const float* __restrict__ Wq, const float* __restrict__ Wk,
    const float* __restrict__ Wv, short* __restrict__ dst)
{
    const int z = blockIdx.y;
    const float* src = (z == 0) ? Wq : ((z == 1) ? Wk : Wv);
    const size_t i = (size_t)blockIdx.x * 256 + threadIdx.x;
    const float4* s = reinterpret_cast<const float4*>(src) + i * 2;
    const float4 a = s[0], b = s[1];
    bf16x8 o;
    o[0] = f2bf(a.x); o[1] = f2bf(a.y); o[2] = f2bf(a.z); o[3] = f2bf(a.w);
    o[4] = f2bf(b.x); o[5] = f2bf(b.y); o[6] = f2bf(b.z); o[7] = f2bf(b.w);
    reinterpret_cast<bf16x8*>(dst + (size_t)z * HID * HID)[i] = o;
}

__global__ __launch_bounds__(256) void maskml_kernel(
    const float* __restrict__ m, float* __restrict__ o)
{
    const float ML = 1.44269504088896340736f;
    const int i = blockIdx.x * 256 + threadIdx.x;   // 1024 threads, float4 each
    float4 v = reinterpret_cast<const float4*>(m)[i];
    v.x *= ML; v.y *= ML; v.z *= ML; v.w *= ML;
    reinterpret_cast<float4*>(o)[i] = v;
}

// ---------------------------------------------------------------------------
// QKV projection, LDS-staged. Tile 128x128, BK=64, dbuf 64KB.
// Q output pre-scaled by 0.125*log2e (folds the softmax scale).
// ---------------------------------------------------------------------------
__global__ __launch_bounds__(256) void qkv_proj_kernel(
    const short* __restrict__ hsb, const short* __restrict__ Wb,
    const float* __restrict__ bq, const float* __restrict__ bk,
    const float* __restrict__ bv,
    short* __restrict__ Qb, short* __restrict__ Kb, short* __restrict__ Vt)
{
    __shared__ __align__(16) char lds[65536];
    const int z = blockIdx.z;
    const float* bias = (z == 0) ? bq : ((z == 1) ? bk : bv);

    const int lane = threadIdx.x & 63;
    const int w    = threadIdx.x >> 6;
    const int lr = lane & 15, hi = lane >> 4;
    const int wi = w >> 1, wj = w & 1;

    const short* Ag; const short* Bg; int ar0, br0;
    if (z < 2) { Ag = Wb + (size_t)z * HID * HID; ar0 = blockIdx.x * 128;
                 Bg = hsb;                        br0 = blockIdx.y * 128; }
    else       { Ag = hsb;                        ar0 = blockIdx.y * 128;
                 Bg = Wb + (size_t)2 * HID * HID; br0 = blockIdx.x * 128; }

    const int rsub = lane >> 3;
    const int c16  = (lane & 7) ^ rsub;

    auto stage = [&](int t, int buf) {
        const int k0 = t * PBK;
#pragma unroll
        for (int c = 0; c < 4; ++c) {
            const int ch = w * 4 + c;
            const int row = ch * 8 + rsub;
            glds16(Ag + (size_t)(ar0 + row) * HID + k0 + c16 * 8,
                   lds + buf * 16384 + ch * 1024);
            glds16(Bg + (size_t)(br0 + row) * HID + k0 + c16 * 8,
                   lds + 32768 + buf * 16384 + ch * 1024);
        }
    };

    stage(0, 0);
    f32x4 acc[4][4] = {};

    for (int t = 0; t < PNT; ++t) {
        asm volatile("s_waitcnt vmcnt(0)" ::: "memory");
        __builtin_amdgcn_s_barrier();
        __builtin_amdgcn_sched_barrier(0);
        if (t + 1 < PNT) stage(t + 1, (t + 1) & 1);
        const char* LA = lds + (t & 1) * 16384;
        const char* LB = lds + 32768 + (t & 1) * 16384;
#pragma unroll
        for (int ks = 0; ks < 2; ++ks) {
            bf16x8 af[4], bf_[4];
#pragma unroll
            for (int i = 0; i < 4; ++i) {
                const int rowA = wi * 64 + i * 16 + lr;
                af[i] = *reinterpret_cast<const bf16x8*>(
                    LA + rowA * 128 + (((ks * 4 + hi) ^ (rowA & 7)) << 4));
                const int rowB = wj * 64 + i * 16 + lr;
                bf_[i] = *reinterpret_cast<const bf16x8*>(
                    LB + rowB * 128 + (((ks * 4 + hi) ^ (rowB & 7)) << 4));
            }
            __builtin_amdgcn_s_setprio(1);
#pragma unroll
            for (int ia = 0; ia < 4; ++ia)
#pragma unroll
                for (int ib = 0; ib < 4; ++ib)
                    acc[ia][ib] = __builtin_amdgcn_mfma_f32_16x16x32_bf16(
                        af[ia], bf_[ib], acc[ia][ib], 0, 0, 0);
            __builtin_amdgcn_s_setprio(0);
        }
    }

    const float SCQ = 0.125f * 1.44269504088896340736f;
    if (z < 2) {
        short* outp = (z == 0) ? Qb : Kb;
        const float sc = (z == 0) ? SCQ : 1.0f;
#pragma unroll
        for (int ia = 0; ia < 4; ++ia) {
            const int nb = ar0 + wi * 64 + ia * 16 + hi * 4;
            const float4 b4 = *reinterpret_cast<const float4*>(bias + nb);
#pragma unroll
            for (int ib = 0; ib < 4; ++ib) {
                const int m = br0 + wj * 64 + ib * 16 + lr;
                s16x4 v;
                v[0] = f2bf((acc[ia][ib][0] + b4.x) * sc);
                v[1] = f2bf((acc[ia][ib][1] + b4.y) * sc);
                v[2] = f2bf((acc[ia][ib][2] + b4.z) * sc);
                v[3] = f2bf((acc[ia][ib][3] + b4.w) * sc);
                *reinterpret_cast<s16x4*>(outp + (size_t)m * HID + nb) = v;
            }
        }
    } else {
#pragma unroll
        for (int ib = 0; ib < 4; ++ib) {
            const int n = br0 + wj * 64 + ib * 16 + lr;
            const float bb = bias[n];
#pragma unroll
            for (int ia = 0; ia < 4; ++ia) {
                const int mb = ar0 + wi * 64 + ia * 16 + hi * 4;
                s16x4 v;
                v[0] = f2bf(acc[ia][ib][0] + bb);
                v[1] = f2bf(acc[ia][ib][1] + bb);
                v[2] = f2bf(acc[ia][ib][2] + bb);
                v[3] = f2bf(acc[ia][ib][3] + bb);
                *reinterpret_cast<s16x4*>(Vt + (size_t)n * SEQ + mb) = v;
            }
        }
    }
}

// ---------------------------------------------------------------------------
// Flash attention: 64q blocks, 4 waves = (qh 2) x (kh 2), each 32q x 32k.
// 3-buffer K/V ring + COUNTED vmcnt(6) (no full drain in the loop): at iter
// t, stage tile t+2 into slot (t+2)%3; slot was last read at tile t-1 and
// the top-of-iter barrier covers it. Mask C-init from global (reg dbuf),
// issued BEFORE the stage glds so the compiler's mask-wait keeps the K/V
// prefetch in flight. Per-lane deferred-max softmax; zero-shuffle P.
// LDS: K ring 3x8KB @0, V ring 3x8KB @24576. 48KB -> 3 blocks/CU.
// ---------------------------------------------------------------------------
__global__ __launch_bounds__(256, 3) void attn_kernel(
    const short* __restrict__ Qb, const short* __restrict__ Kb,
    const short* __restrict__ Vt, const float* __restrict__ maskml,
    float* __restrict__ out)
{
    __shared__ __align__(16) char lds[49152];
    const int tid  = threadIdx.x;
    const int lane = tid & 63;
    const int w    = tid >> 6;
    const int lr = lane & 15, hi = lane >> 4;
    const int qh = w >> 1, kh = w & 1;       // wave = (q-half, key-half)
    const int h  = blockIdx.y;
    const int q0 = blockIdx.x * 64 + qh * 32;

    // ---- staging: per-lane source offsets (elements) + LDS dests (3 slots)
    const int srow = lane >> 3;
    int sofK[2], sofV[2];
    char* sdK_[3][2]; char* sdV_[3][2];
#pragma unroll
    for (int j = 0; j < 2; ++j) {
        const int ch  = w * 2 + j;
        const int row = ch * 8 + srow;
        const int c16 = (lane & 7) ^ srow ^ ((ch & 1) << 2);
        sofK[j] = row * HID + h * HDIM + c16 * 8;
        sofV[j] = (h * HDIM + row) * SEQ + c16 * 8;
#pragma unroll
        for (int b = 0; b < 3; ++b) {
            sdK_[b][j] = lds + b * 8192 + ch * 1024;
            sdV_[b][j] = lds + 24576 + b * 8192 + ch * 1024;
        }
    }

    auto stagep = [&](int slot, int tn) {
        const short* k = Kb + (size_t)tn * (KVB * HID);
        const short* v = Vt + tn * KVB;
        glds16(k + sofK[0], sdK_[slot][0]);
        glds16(k + sofK[1], sdK_[slot][1]);
        glds16(v + sofV[0], sdV_[slot][0]);
        glds16(v + sofV[1], sdV_[slot][1]);
    };
    const int oM = kh * 32 + hi * 8;
    auto loadM = [&](int tn, f32x4& a, f32x4& b) {
        const float* m = maskml + tn * KVB + oM;
        a = *reinterpret_cast<const f32x4*>(m);
        b = *reinterpret_cast<const f32x4*>(m + 4);
    };

    // ---- Q fragments first (oldest in vmcnt queue; pre-scaled at projection)
    const short* qp = Qb + (size_t)(q0 + lr) * HID + h * HDIM + hi * 8;
    const bf16x8 qf0 = *reinterpret_cast<const bf16x8*>(qp);
    const bf16x8 qf1 = *reinterpret_cast<const bf16x8*>(qp + 32);
    const bf16x8 qg0 = *reinterpret_cast<const bf16x8*>(qp + 16 * HID);
    const bf16x8 qg1 = *reinterpret_cast<const bf16x8*>(qp + 16 * HID + 32);

    // ---- prologue: stage(0), mask(0), stage(1)  (issue order matters)
    f32x4 cm0, cm1;
    stagep(0, 0);
    loadM(0, cm0, cm1);
    stagep(1, 1);

    // ---- precomputed LDS read pointers (3 slots, all fragments)
    const int kbase = ((lr >> 2) * 8) + (lr & 3) + kh * 32;  // key-permutation
    const int fv    = (lr & 7) ^ (((lr >> 3) & 1) << 2);     // V-row swizzle
    const int vslot = ((kh * 4 + hi) ^ fv) << 4;
    const char* kp[3][2][2];
    const char* vp[3][4];
#pragma unroll
    for (int b = 0; b < 3; ++b) {
#pragma unroll
        for (int kg = 0; kg < 2; ++kg) {
            const int row = kbase + kg * 4;
            const int fr  = (row & 7) ^ ((row >> 1) & 4);
            kp[b][kg][0] = lds + b * 8192 + row * 128 + ((hi ^ fr) << 4);
            kp[b][kg][1] = lds + b * 8192 + row * 128 + (((4 + hi) ^ fr) << 4);
        }
#pragma unroll
        for (int dg = 0; dg < 4; ++dg)
            vp[b][dg] = lds + 24576 + b * 8192 + (dg * 16 + lr) * 128 + vslot;
    }

    f32x4 acc[4][2] = {};                     // [dg][qg]
    float m_r[2] = {-INFINITY, -INFINITY};
    float ls[2]  = {0.f, 0.f};

    auto tile = [&](int tt, const int rs, const int ws) {
        asm volatile("s_waitcnt vmcnt(6)" ::: "memory");  // stage(tt) landed
        __builtin_amdgcn_s_barrier();
        __builtin_amdgcn_sched_barrier(0);
        // mask prefetch for tt+1 (wrapped), issued BEFORE the stage glds
        f32x4 nm0, nm1;
        loadM((tt + 1) & (NT - 1), nm0, nm1);
        __builtin_amdgcn_sched_barrier(0);
        stagep(ws, (tt + 2) & (NT - 1));
        __builtin_amdgcn_sched_barrier(0);

        // ---- QK^T (key-permuted), C-init = mask*log2e (cm regs)
        const bf16x8 kf00 = *reinterpret_cast<const bf16x8*>(kp[rs][0][0]);
        const bf16x8 kf01 = *reinterpret_cast<const bf16x8*>(kp[rs][0][1]);
        const bf16x8 kf10 = *reinterpret_cast<const bf16x8*>(kp[rs][1][0]);
        const bf16x8 kf11 = *reinterpret_cast<const bf16x8*>(kp[rs][1][1]);
        f32x4 z[2][2];   // [kg][qg]
        z[0][0] = cm0; z[0][1] = cm0; z[1][0] = cm1; z[1][1] = cm1;
        __builtin_amdgcn_s_setprio(1);
        z[0][0] = __builtin_amdgcn_mfma_f32_16x16x32_bf16(kf00, qf0, z[0][0], 0, 0, 0);
        z[0][0] = __builtin_amdgcn_mfma_f32_16x16x32_bf16(kf01, qf1, z[0][0], 0, 0, 0);
        z[0][1] = __builtin_amdgcn_mfma_f32_16x16x32_bf16(kf00, qg0, z[0][1], 0, 0, 0);
        z[0][1] = __builtin_amdgcn_mfma_f32_16x16x32_bf16(kf01, qg1, z[0][1], 0, 0, 0);
        z[1][0] = __builtin_amdgcn_mfma_f32_16x16x32_bf16(kf10, qf0, z[1][0], 0, 0, 0);
        z[1][0] = __builtin_amdgcn_mfma_f32_16x16x32_bf16(kf11, qf1, z[1][0], 0, 0, 0);
        z[1][1] = __builtin_amdgcn_mfma_f32_16x16x32_bf16(kf10, qg0, z[1][1], 0, 0, 0);
        z[1][1] = __builtin_amdgcn_mfma_f32_16x16x32_bf16(kf11, qg1, z[1][1], 0, 0, 0);
        __builtin_amdgcn_s_setprio(0);

        // ---- e = exp2(z - m), per-lane (no cross-lane ops in common path)
        float e_[2][2][4];
#pragma unroll
        for (int kg = 0; kg < 2; ++kg)
#pragma unroll
            for (int qg = 0; qg < 2; ++qg)
#pragma unroll
                for (int r = 0; r < 4; ++r)
                    e_[kg][qg][r] = exp2f(z[kg][qg][r] - m_r[qg]);

        // ---- per-lane violation check: any e > 2^8?
        const float pa = max3f(e_[0][0][0], e_[0][0][1], e_[0][0][2]);
        const float pb = max3f(e_[0][0][3], e_[0][1][0], e_[0][1][1]);
        const float pc = max3f(e_[0][1][2], e_[0][1][3], e_[1][0][0]);
        const float pd = max3f(e_[1][0][1], e_[1][0][2], e_[1][0][3]);
        const float pe = max3f(e_[1][1][0], e_[1][1][1], e_[1][1][2]);
        const float pmax = max3f(fmaxf(pa, pb), fmaxf(pc, pd),
                                 fmaxf(pe, e_[1][1][3]));
        if (__ballot(pmax > 256.f)) {
            // rare recovery: full cross-lane max, rescale, recompute e
#pragma unroll
            for (int qg = 0; qg < 2; ++qg) {
                float t_ = fmaxf(
                    max3f(z[0][qg][0], z[0][qg][1], z[0][qg][2]),
                    max3f(fmaxf(z[0][qg][3], z[1][qg][0]),
                          fmaxf(z[1][qg][1], z[1][qg][2]), z[1][qg][3]));
                t_ = fmaxf(t_, __shfl_xor(t_, 16));
                t_ = fmaxf(t_, __shfl_xor(t_, 32));
                const float newm = fmaxf(m_r[qg], t_);
                const float sc = exp2f(fmaxf(m_r[qg] - newm, -128.f));
                ls[qg] *= sc;
#pragma unroll
                for (int dg = 0; dg < 4; ++dg) acc[dg][qg] *= sc;
                m_r[qg] = newm;
#pragma unroll
                for (int kg = 0; kg < 2; ++kg)
#pragma unroll
                    for (int r = 0; r < 4; ++r)
                        e_[kg][qg][r] = exp2f(z[kg][qg][r] - newm);
            }
        }

        // ---- accumulate l, pack P (zero-shuffle)
        union { unsigned u[4]; bf16x8 v; } P[2];
#pragma unroll
        for (int qg = 0; qg < 2; ++qg) {
            ls[qg] += ((e_[0][qg][0] + e_[0][qg][1]) + (e_[0][qg][2] + e_[0][qg][3]))
                    + ((e_[1][qg][0] + e_[1][qg][1]) + (e_[1][qg][2] + e_[1][qg][3]));
            P[qg].u[0] = cvtpk(e_[0][qg][0], e_[0][qg][1]);
            P[qg].u[1] = cvtpk(e_[0][qg][2], e_[0][qg][3]);
            P[qg].u[2] = cvtpk(e_[1][qg][0], e_[1][qg][1]);
            P[qg].u[3] = cvtpk(e_[1][qg][2], e_[1][qg][3]);
        }

        // ---- PV: O[d][q] += V[d][k]·P[k][q] over this wave's 32 keys
#pragma unroll
        for (int dg = 0; dg < 4; ++dg) {
            const bf16x8 vf = *reinterpret_cast<const bf16x8*>(vp[rs][dg]);
            __builtin_amdgcn_s_setprio(1);
            acc[dg][0] = __builtin_amdgcn_mfma_f32_16x16x32_bf16(vf, P[0].v, acc[dg][0], 0, 0, 0);
            acc[dg][1] = __builtin_amdgcn_mfma_f32_16x16x32_bf16(vf, P[1].v, acc[dg][1], 0, 0, 0);
            __builtin_amdgcn_s_setprio(0);
        }
        cm0 = nm0; cm1 = nm1;
    };

    int t = 0;
#pragma unroll 1
    for (int i = 0; i < 21; ++i) {
        tile(t, 0, 2); ++t;
        tile(t, 1, 0); ++t;
        tile(t, 2, 1); ++t;
    }
    tile(63, 0, 2);

    // ---- reduce l across hi-groups (per qg)
#pragma unroll
    for (int qg = 0; qg < 2; ++qg) {
        float t_ = ls[qg];
        t_ += __shfl_xor(t_, 16);
        t_ += __shfl_xor(t_, 32);
        ls[qg] = t_;
    }

    // ---- flash-merge the two key-halves through LDS (reuse ring space)
    __syncthreads();   // all reads done + glds drained before overlay
    float* mg  = (float*)lds;                 // [qh][dg*2+qg][lane] f32x4 = 16KB
    float* mlb = (float*)(lds + 16384);       // [qh][qg][lane][2] = 2KB
    if (kh == 1) {
#pragma unroll
        for (int qg = 0; qg < 2; ++qg) {
            float2 v0; v0.x = m_r[qg]; v0.y = ls[qg];
            *reinterpret_cast<float2*>(mlb + (((qh * 2 + qg) * 64 + lane) * 2)) = v0;
        }
#pragma unroll
        for (int dg = 0; dg < 4; ++dg)
#pragma unroll
            for (int qg = 0; qg < 2; ++qg)
                *reinterpret_cast<f32x4*>(
                    mg + ((qh * 8 + dg * 2 + qg) * 64 + lane) * 4) = acc[dg][qg];
    }
    __syncthreads();
    if (kh == 0) {
        float sc0[2], sc1[2], rl[2];
#pragma unroll
        for (int qg = 0; qg < 2; ++qg) {
            const float2 v = *reinterpret_cast<const float2*>(
                mlb + (((qh * 2 + qg) * 64 + lane) * 2));
            const float mm = fmaxf(m_r[qg], v.x);
            sc0[qg] = exp2f(fmaxf(m_r[qg] - mm, -128.f));
            sc1[qg] = exp2f(fmaxf(v.x - mm, -128.f));
            rl[qg] = 1.0f / (ls[qg] * sc0[qg] + v.y * sc1[qg]);
        }
#pragma unroll
        for (int dg = 0; dg < 4; ++dg) {
#pragma unroll
            for (int qg = 0; qg < 2; ++qg) {
                const f32x4 o1 = *reinterpret_cast<const f32x4*>(
                    mg + ((qh * 8 + dg * 2 + qg) * 64 + lane) * 4);
                const f32x4 of = (acc[dg][qg] * sc0[qg] + o1 * sc1[qg]) * rl[qg];
                float* op = out + (size_t)(q0 + qg * 16 + lr) * HID
                          + h * HDIM + dg * 16 + hi * 4;
                *reinterpret_cast<f32x4*>(op) = of;
            }
        }
    }
}

// ---------------------------------------------------------------------------
extern "C" void kernel_launch(void* const* d_in, const int* in_sizes, int n_in,
                              void* d_out, int out_size, void* d_ws, size_t ws_size,
                              hipStream_t stream) {
    const float* hs   = (const float*)d_in[0];
    const float* mask = (const float*)d_in[1];
    const float* Wq   = (const float*)d_in[2];
    const float* bq   = (const float*)d_in[3];
    const float* Wk   = (const float*)d_in[4];
    const float* bk   = (const float*)d_in[5];
    const float* Wv   = (const float*)d_in[6];
    const float* bv   = (const float*)d_in[7];

    short* Qb = (short*)d_ws;                       // bf16 [SEQ][HID], pre-scaled
    short* Kb = Qb + (size_t)SEQ * HID;             // bf16 [SEQ][HID]
    short* Vt = Kb + (size_t)SEQ * HID;             // bf16 [HID][SEQ]
    float* maskML = (float*)(Vt + (size_t)HID * SEQ);  // f32 [SEQ]
    float* out = (float*)d_out;

    // bf16 scratch carved from d_out (attn overwrites it at the very end)
    short* hsb = (short*)d_out;
    short* Wb  = hsb + (size_t)SEQ * HID;

    cast_bf16_kernel<<<dim3(SEQ * HID / 2048), 256, 0, stream>>>(hs, hsb);
    cast_w_kernel<<<dim3(HID * HID / 2048, 3), 256, 0, stream>>>(Wq, Wk, Wv, Wb);
    maskml_kernel<<<dim3(SEQ / 1024), 256, 0, stream>>>(mask, maskML);

    qkv_proj_kernel<<<dim3(HID / 128, SEQ / 128, 3), 256, 0, stream>>>(
        hsb, Wb, bq, bk, bv, Qb, Kb, Vt);

    attn_kernel<<<dim3(SEQ / KVB, NHEAD), 256, 0, stream>>>(Qb, Kb, Vt, maskML, out);
}

// Round 11
// 133.960 us; speedup vs baseline: 1.7064x; 1.0397x over previous
//
#include <hip/hip_runtime.h>
#include <hip/hip_bf16.h>
#include <math.h>

#define SEQ 4096
#define HID 768
#define NHEAD 12
#define HDIM 64
#define KVB 64
#define NT (SEQ / KVB)   // 64
#define PBK 64
#define PNT (HID / PBK)  // 12

typedef __attribute__((ext_vector_type(8))) short bf16x8;
typedef __attribute__((ext_vector_type(4))) float f32x4;
typedef __attribute__((ext_vector_type(16))) float f32x16;
typedef __attribute__((ext_vector_type(4))) short s16x4;

static __device__ __forceinline__ short f2bf(float f) {
    unsigned u = __builtin_bit_cast(unsigned, f);
    unsigned r = (u + 0x7fffu + ((u >> 16) & 1u)) >> 16;
    return (short)r;
}
static __device__ __forceinline__ unsigned cvtpk(float lo, float hi) {
    unsigned r;
    asm("v_cvt_pk_bf16_f32 %0, %1, %2" : "=v"(r) : "v"(lo), "v"(hi));
    return r;
}
static __device__ __forceinline__ float max3f(float a, float b, float c) {
    float r;
    asm("v_max3_f32 %0, %1, %2, %3" : "=v"(r) : "v"(a), "v"(b), "v"(c));
    return r;
}
static __device__ __forceinline__ void glds16(const void* g, void* l) {
    __builtin_amdgcn_global_load_lds(
        (const __attribute__((address_space(1))) unsigned*)g,
        (__attribute__((address_space(3))) unsigned*)l, 16, 0, 0);
}

// ---------------------------------------------------------------------------
// fp32 -> bf16 casts
// ---------------------------------------------------------------------------
__global__ __launch_bounds__(256) void cast_bf16_kernel(
    const float* __restrict__ src, short* __restrict__ dst)
{
    const size_t i = (size_t)blockIdx.x * 256 + threadIdx.x;
    const float4* s = reinterpret_cast<const float4*>(src) + i * 2;
    const float4 a = s[0], b = s[1];
    bf16x8 o;
    o[0] = f2bf(a.x); o[1] = f2bf(a.y); o[2] = f2bf(a.z); o[3] = f2bf(a.w);
    o[4] = f2bf(b.x); o[5] = f2bf(b.y); o[6] = f2bf(b.z); o[7] = f2bf(b.w);
    reinterpret_cast<bf16x8*>(dst)[i] = o;
}

__global__ __launch_bounds__(256) void cast_w_kernel(
    const float* __restrict__ Wq, const float* __restrict__ Wk,
    const float* __restrict__ Wv, short* __restrict__ dst)
{
    const int z = blockIdx.y;
    const float* src = (z == 0) ? Wq : ((z == 1) ? Wk : Wv);
    const size_t i = (size_t)blockIdx.x * 256 + threadIdx.x;
    const float4* s = reinterpret_cast<const float4*>(src) + i * 2;
    const float4 a = s[0], b = s[1];
    bf16x8 o;
    o[0] = f2bf(a.x); o[1] = f2bf(a.y); o[2] = f2bf(a.z); o[3] = f2bf(a.w);
    o[4] = f2bf(b.x); o[5] = f2bf(b.y); o[6] = f2bf(b.z); o[7] = f2bf(b.w);
    reinterpret_cast<bf16x8*>(dst + (size_t)z * HID * HID)[i] = o;
}

// ---------------------------------------------------------------------------
// QKV projection, LDS-staged. Tile 128x128, BK=64, dbuf 64KB.
// Q output pre-scaled by 0.125*log2e (folds the softmax scale).
// ---------------------------------------------------------------------------
__global__ __launch_bounds__(256) void qkv_proj_kernel(
    const short* __restrict__ hsb, const short* __restrict__ Wb,
    const float* __restrict__ bq, const float* __restrict__ bk,
    const float* __restrict__ bv,
    short* __restrict__ Qb, short* __restrict__ Kb, short* __restrict__ Vt)
{
    __shared__ __align__(16) char lds[65536];
    const int z = blockIdx.z;
    const float* bias = (z == 0) ? bq : ((z == 1) ? bk : bv);

    const int lane = threadIdx.x & 63;
    const int w    = threadIdx.x >> 6;
    const int lr = lane & 15, hi = lane >> 4;
    const int wi = w >> 1, wj = w & 1;

    const short* Ag; const short* Bg; int ar0, br0;
    if (z < 2) { Ag = Wb + (size_t)z * HID * HID; ar0 = blockIdx.x * 128;
                 Bg = hsb;                        br0 = blockIdx.y * 128; }
    else       { Ag = hsb;                        ar0 = blockIdx.y * 128;
                 Bg = Wb + (size_t)2 * HID * HID; br0 = blockIdx.x * 128; }

    const int rsub = lane >> 3;
    const int c16  = (lane & 7) ^ rsub;

    auto stage = [&](int t, int buf) {
        const int k0 = t * PBK;
#pragma unroll
        for (int c = 0; c < 4; ++c) {
            const int ch = w * 4 + c;
            const int row = ch * 8 + rsub;
            glds16(Ag + (size_t)(ar0 + row) * HID + k0 + c16 * 8,
                   lds + buf * 16384 + ch * 1024);
            glds16(Bg + (size_t)(br0 + row) * HID + k0 + c16 * 8,
                   lds + 32768 + buf * 16384 + ch * 1024);
        }
    };

    stage(0, 0);
    f32x4 acc[4][4] = {};

    for (int t = 0; t < PNT; ++t) {
        asm volatile("s_waitcnt vmcnt(0)" ::: "memory");
        __builtin_amdgcn_s_barrier();
        __builtin_amdgcn_sched_barrier(0);
        if (t + 1 < PNT) stage(t + 1, (t + 1) & 1);
        const char* LA = lds + (t & 1) * 16384;
        const char* LB = lds + 32768 + (t & 1) * 16384;
#pragma unroll
        for (int ks = 0; ks < 2; ++ks) {
            bf16x8 af[4], bf_[4];
#pragma unroll
            for (int i = 0; i < 4; ++i) {
                const int rowA = wi * 64 + i * 16 + lr;
                af[i] = *reinterpret_cast<const bf16x8*>(
                    LA + rowA * 128 + (((ks * 4 + hi) ^ (rowA & 7)) << 4));
                const int rowB = wj * 64 + i * 16 + lr;
                bf_[i] = *reinterpret_cast<const bf16x8*>(
                    LB + rowB * 128 + (((ks * 4 + hi) ^ (rowB & 7)) << 4));
            }
            __builtin_amdgcn_s_setprio(1);
#pragma unroll
            for (int ia = 0; ia < 4; ++ia)
#pragma unroll
                for (int ib = 0; ib < 4; ++ib)
                    acc[ia][ib] = __builtin_amdgcn_mfma_f32_16x16x32_bf16(
                        af[ia], bf_[ib], acc[ia][ib], 0, 0, 0);
            __builtin_amdgcn_s_setprio(0);
        }
    }

    const float SCQ = 0.125f * 1.44269504088896340736f;
    if (z < 2) {
        short* outp = (z == 0) ? Qb : Kb;
        const float sc = (z == 0) ? SCQ : 1.0f;
#pragma unroll
        for (int ia = 0; ia < 4; ++ia) {
            const int nb = ar0 + wi * 64 + ia * 16 + hi * 4;
            const float4 b4 = *reinterpret_cast<const float4*>(bias + nb);
#pragma unroll
            for (int ib = 0; ib < 4; ++ib) {
                const int m = br0 + wj * 64 + ib * 16 + lr;
                s16x4 v;
                v[0] = f2bf((acc[ia][ib][0] + b4.x) * sc);
                v[1] = f2bf((acc[ia][ib][1] + b4.y) * sc);
                v[2] = f2bf((acc[ia][ib][2] + b4.z) * sc);
                v[3] = f2bf((acc[ia][ib][3] + b4.w) * sc);
                *reinterpret_cast<s16x4*>(outp + (size_t)m * HID + nb) = v;
            }
        }
    } else {
#pragma unroll
        for (int ib = 0; ib < 4; ++ib) {
            const int n = br0 + wj * 64 + ib * 16 + lr;
            const float bb = bias[n];
#pragma unroll
            for (int ia = 0; ia < 4; ++ia) {
                const int mb = ar0 + wi * 64 + ia * 16 + hi * 4;
                s16x4 v;
                v[0] = f2bf(acc[ia][ib][0] + bb);
                v[1] = f2bf(acc[ia][ib][1] + bb);
                v[2] = f2bf(acc[ia][ib][2] + bb);
                v[3] = f2bf(acc[ia][ib][3] + bb);
                *reinterpret_cast<s16x4*>(Vt + (size_t)n * SEQ + mb) = v;
            }
        }
    }
}

// ---------------------------------------------------------------------------
// Flash attention, 32x32x16 MFMA version. r8 geometry: 64q blocks, 4 waves =
// (qh 2) x (kh 2), each wave 32q x 32k per tile. Lane owns ONE q (lane&31);
// hl = lane>>5 selects which 16 of 32 keys. QK^T = single f32x16 acc, 4
// chained MFMAs (A = key-permuted K rows via involution pi so each lane's 16
// scores ARE its two PV B-fragments in natural order). PV = 2 dgrp x 2 ksl.
// Softmax: scalar m/l per lane; m init 0; per-lane deferred check (e>256);
// rare recovery = exact pow2 rescale via ilogbf (no score retention needed).
// LDS: K dbuf 2x8KB @0, V dbuf 2x8KB @16384, mask*log2e f32 16KB @32768.
// ---------------------------------------------------------------------------
__global__ __launch_bounds__(256, 3) void attn_kernel(
    const short* __restrict__ Qb, const short* __restrict__ Kb,
    const short* __restrict__ Vt, const float* __restrict__ maskp,
    float* __restrict__ out)
{
    __shared__ __align__(16) char lds[49152];
    const int tid  = threadIdx.x;
    const int lane = tid & 63;
    const int w    = tid >> 6;
    const int qh = w >> 1, kh = w & 1;
    const int hl = lane >> 5, q = lane & 31;
    const int head = blockIdx.y;
    const int q0w  = blockIdx.x * 64 + qh * 32;
    const float ML = 1.44269504088896340736f;

    // ---- staging (identical to r8): per-lane offsets + LDS dests
    const int srow = lane >> 3;
    int sofK[2], sofV[2];
    char* sdK[2][2]; char* sdV[2][2];
#pragma unroll
    for (int j = 0; j < 2; ++j) {
        const int ch  = w * 2 + j;
        const int row = ch * 8 + srow;
        const int c16 = (lane & 7) ^ srow ^ ((ch & 1) << 2);
        sofK[j] = row * HID + c16 * 8;
        sofV[j] = row * SEQ + c16 * 8;
#pragma unroll
        for (int b = 0; b < 2; ++b) {
            sdK[b][j] = lds + b * 8192 + ch * 1024;
            sdV[b][j] = lds + 16384 + b * 8192 + ch * 1024;
        }
    }
    const short* gK = Kb + head * HDIM;
    const short* gV = Vt + (size_t)head * HDIM * SEQ;
    auto stagep = [&](int buf) {
        glds16(gK + sofK[0], sdK[buf][0]);
        glds16(gK + sofK[1], sdK[buf][1]);
        glds16(gV + sofV[0], sdV[buf][0]);
        glds16(gV + sofV[1], sdV[buf][1]);
        gK += KVB * HID; gV += KVB;
    };

    stagep(0);   // tile 0 in flight across mask/Q staging

    // ---- stage mask*log2e as f32 (once)
    {
        float* mb = (float*)(lds + 32768);
        const int base = tid * 16;
#pragma unroll
        for (int i = 0; i < 4; ++i) {
            float4 m4 = *reinterpret_cast<const float4*>(maskp + base + i * 4);
            m4.x *= ML; m4.y *= ML; m4.z *= ML; m4.w *= ML;
            *reinterpret_cast<float4*>(mb + base + i * 4) = m4;
        }
    }

    // ---- Q B-fragments: Q[q0w+q][d = s*16 + hl*8 .. +7], pre-scaled
    const short* qp = Qb + (size_t)(q0w + q) * HID + head * HDIM + hl * 8;
    const bf16x8 qv0 = *reinterpret_cast<const bf16x8*>(qp);
    const bf16x8 qv1 = *reinterpret_cast<const bf16x8*>(qp + 16);
    const bf16x8 qv2 = *reinterpret_cast<const bf16x8*>(qp + 32);
    const bf16x8 qv3 = *reinterpret_cast<const bf16x8*>(qp + 48);

    __syncthreads();   // mask visible to all waves

    // ---- K A-row (key-permutation involution pi) + LDS read pointers
    const int pr = (q & 3) + ((q >> 2) & 1) * 8 + ((q >> 3) & 1) * 4
                 + ((q >> 4) & 1) * 16;
    const int krow = kh * 32 + pr;
    const int fr   = (krow & 7) ^ ((krow >> 1) & 4);
    const char* kp[2][4];
    const char* vp[2][2][2];
#pragma unroll
    for (int b = 0; b < 2; ++b) {
#pragma unroll
        for (int s = 0; s < 4; ++s)
            kp[b][s] = lds + b * 8192 + krow * 128 + (((s * 2 + hl) ^ fr) << 4);
#pragma unroll
        for (int dgrp = 0; dgrp < 2; ++dgrp) {
            const int vr  = dgrp * 32 + q;
            const int fvr = (vr & 7) ^ ((vr >> 1) & 4);
#pragma unroll
            for (int ksl = 0; ksl < 2; ++ksl)
                vp[b][dgrp][ksl] = lds + 16384 + b * 8192 + vr * 128
                                 + (((kh * 4 + ksl * 2 + hl) ^ fvr) << 4);
        }
    }

    f32x16 acc0 = {}, acc1 = {};
    float m_r = 0.f, ls = 0.f;

    auto tile = [&](int tt, int buf) {
        asm volatile("s_waitcnt vmcnt(0)" ::: "memory");  // stage(tt) landed
        __builtin_amdgcn_s_barrier();
        __builtin_amdgcn_sched_barrier(0);
        if (tt + 1 < NT) stagep(buf ^ 1);

        // ---- C-init from mask*log2e: regs 0-7 <-> keys kh*32+hl*8+r,
        //      regs 8-15 <-> keys kh*32+16+hl*8+(r-8)
        const float* mk = (const float*)(lds + 32768) + tt * KVB + kh * 32 + hl * 8;
        const f32x4 c0 = *reinterpret_cast<const f32x4*>(mk);
        const f32x4 c1 = *reinterpret_cast<const f32x4*>(mk + 4);
        const f32x4 c2 = *reinterpret_cast<const f32x4*>(mk + 16);
        const f32x4 c3 = *reinterpret_cast<const f32x4*>(mk + 20);
        f32x16 z;
#pragma unroll
        for (int r = 0; r < 4; ++r) {
            z[r] = c0[r]; z[4 + r] = c1[r]; z[8 + r] = c2[r]; z[12 + r] = c3[r];
        }

        // ---- QK^T: 4 chained 32x32x16 MFMAs (A = permuted K, B = Q)
        const bf16x8 k0 = *reinterpret_cast<const bf16x8*>(kp[buf][0]);
        const bf16x8 k1 = *reinterpret_cast<const bf16x8*>(kp[buf][1]);
        const bf16x8 k2 = *reinterpret_cast<const bf16x8*>(kp[buf][2]);
        const bf16x8 k3 = *reinterpret_cast<const bf16x8*>(kp[buf][3]);
        __builtin_amdgcn_s_setprio(1);
        z = __builtin_amdgcn_mfma_f32_32x32x16_bf16(k0, qv0, z, 0, 0, 0);
        z = __builtin_amdgcn_mfma_f32_32x32x16_bf16(k1, qv1, z, 0, 0, 0);
        z = __builtin_amdgcn_mfma_f32_32x32x16_bf16(k2, qv2, z, 0, 0, 0);
        z = __builtin_amdgcn_mfma_f32_32x32x16_bf16(k3, qv3, z, 0, 0, 0);
        __builtin_amdgcn_s_setprio(0);

        // ---- e = exp2(z - m), per-lane; no cross-lane ops in common path
        float e[16];
#pragma unroll
        for (int r = 0; r < 16; ++r) e[r] = exp2f(z[r] - m_r);

        const float pa = max3f(e[0], e[1], e[2]);
        const float pb = max3f(e[3], e[4], e[5]);
        const float pc = max3f(e[6], e[7], e[8]);
        const float pd = max3f(e[9], e[10], e[11]);
        const float pe = max3f(e[12], e[13], e[14]);
        const float pmax = max3f(max3f(pa, pb, pc), max3f(pd, pe, e[15]),
                                 0.0f);
        if (__ballot(pmax > 256.f)) {
            // rare recovery: exact pow2 rescale (lane pair shares state)
            const float pm = fmaxf(pmax, __shfl_xor(pmax, 32));
            int ex = ilogbf(pm) + 1;
            if (ex < 0) ex = 0;
            const float dsc = exp2f((float)-ex);
            m_r += (float)ex;
            ls *= dsc;
            acc0 *= dsc; acc1 *= dsc;
#pragma unroll
            for (int r = 0; r < 16; ++r) e[r] *= dsc;
        }

        // ---- accumulate l, pack P (natural order = PV B-fragments)
        ls += (((e[0] + e[1]) + (e[2] + e[3])) + ((e[4] + e[5]) + (e[6] + e[7])))
            + (((e[8] + e[9]) + (e[10] + e[11])) + ((e[12] + e[13]) + (e[14] + e[15])));
        union { unsigned u[4]; bf16x8 v; } P0, P1;
#pragma unroll
        for (int j = 0; j < 4; ++j) {
            P0.u[j] = cvtpk(e[2 * j], e[2 * j + 1]);
            P1.u[j] = cvtpk(e[8 + 2 * j], e[9 + 2 * j]);
        }

        // ---- PV: acc[dgrp] += V . P  (2 chained per dgrp)
        const bf16x8 v00 = *reinterpret_cast<const bf16x8*>(vp[buf][0][0]);
        const bf16x8 v01 = *reinterpret_cast<const bf16x8*>(vp[buf][0][1]);
        const bf16x8 v10 = *reinterpret_cast<const bf16x8*>(vp[buf][1][0]);
        const bf16x8 v11 = *reinterpret_cast<const bf16x8*>(vp[buf][1][1]);
        __builtin_amdgcn_s_setprio(1);
        acc0 = __builtin_amdgcn_mfma_f32_32x32x16_bf16(v00, P0.v, acc0, 0, 0, 0);
        acc0 = __builtin_amdgcn_mfma_f32_32x32x16_bf16(v01, P1.v, acc0, 0, 0, 0);
        acc1 = __builtin_amdgcn_mfma_f32_32x32x16_bf16(v10, P0.v, acc1, 0, 0, 0);
        acc1 = __builtin_amdgcn_mfma_f32_32x32x16_bf16(v11, P1.v, acc1, 0, 0, 0);
        __builtin_amdgcn_s_setprio(0);
    };

    for (int t = 0; t < NT; t += 2) {
        tile(t, 0);
        tile(t + 1, 1);
    }

    // ---- partner-lane l reduce (other 16 keys of my q live in lane^32)
    ls += __shfl_xor(ls, 32);

    // ---- flash-merge the two key-halves through LDS (overlay K/V buffers)
    __syncthreads();
    float* mg  = (float*)lds;                 // [qh][dgrp][lane] f32x16 = 16KB
    float* mlb = (float*)(lds + 16384);       // [qh][lane] float2 = 1KB
    if (kh) {
        float2 st; st.x = m_r; st.y = ls;
        *reinterpret_cast<float2*>(mlb + (qh * 64 + lane) * 2) = st;
        *reinterpret_cast<f32x16*>(mg + ((qh * 2 + 0) * 64 + lane) * 16) = acc0;
        *reinterpret_cast<f32x16*>(mg + ((qh * 2 + 1) * 64 + lane) * 16) = acc1;
    }
    __syncthreads();
    if (!kh) {
        const float2 o1 = *reinterpret_cast<const float2*>(
            mlb + (qh * 64 + lane) * 2);
        const float mw = fmaxf(m_r, o1.x);
        const float s0 = exp2f(m_r - mw);
        const float s1 = exp2f(o1.x - mw);
        const float rl = 1.0f / (ls * s0 + o1.y * s1);
        const f32x16 a1 = *reinterpret_cast<const f32x16*>(
            mg + ((qh * 2 + 0) * 64 + lane) * 16);
        const f32x16 b1 = *reinterpret_cast<const f32x16*>(
            mg + ((qh * 2 + 1) * 64 + lane) * 16);
        const f32x16 o0 = (acc0 * s0 + a1 * s1) * rl;
        const f32x16 o2 = (acc1 * s0 + b1 * s1) * rl;
        float* op = out + (size_t)(q0w + q) * HID + head * HDIM;
#pragma unroll
        for (int rq = 0; rq < 4; ++rq) {
            f32x4 v0, v1;
#pragma unroll
            for (int j = 0; j < 4; ++j) { v0[j] = o0[rq * 4 + j]; v1[j] = o2[rq * 4 + j]; }
            const int d0 = rq * 8 + hl * 4;
            *reinterpret_cast<f32x4*>(op + d0)      = v0;
            *reinterpret_cast<f32x4*>(op + 32 + d0) = v1;
        }
    }
}

// ---------------------------------------------------------------------------
extern "C" void kernel_launch(void* const* d_in, const int* in_sizes, int n_in,
                              void* d_out, int out_size, void* d_ws, size_t ws_size,
                              hipStream_t stream) {
    const float* hs   = (const float*)d_in[0];
    const float* mask = (const float*)d_in[1];
    const float* Wq   = (const float*)d_in[2];
    const float* bq   = (const float*)d_in[3];
    const float* Wk   = (const float*)d_in[4];
    const float* bk   = (const float*)d_in[5];
    const float* Wv   = (const float*)d_in[6];
    const float* bv   = (const float*)d_in[7];

    short* Qb = (short*)d_ws;                       // bf16 [SEQ][HID], pre-scaled
    short* Kb = Qb + (size_t)SEQ * HID;             // bf16 [SEQ][HID]
    short* Vt = Kb + (size_t)SEQ * HID;             // bf16 [HID][SEQ]
    float* out = (float*)d_out;

    // bf16 scratch carved from d_out (attn overwrites it at the very end)
    short* hsb = (short*)d_out;
    short* Wb  = hsb + (size_t)SEQ * HID;

    cast_bf16_kernel<<<dim3(SEQ * HID / 2048), 256, 0, stream>>>(hs, hsb);
    cast_w_kernel<<<dim3(HID * HID / 2048, 3), 256, 0, stream>>>(Wq, Wk, Wv, Wb);

    qkv_proj_kernel<<<dim3(HID / 128, SEQ / 128, 3), 256, 0, stream>>>(
        hsb, Wb, bq, bk, bv, Qb, Kb, Vt);

    attn_kernel<<<dim3(SEQ / KVB, NHEAD), 256, 0, stream>>>(Qb, Kb, Vt, mask, out);
}